// Round 22
// baseline (515.868 us; speedup 1.0000x reference)
//
#include <hip/hip_runtime.h>
#include <hip/hip_fp16.h>

#define K_DIM 4096
#define N_DIM 11008
#define NZ8   1376          // N_DIM/8
#define NKT   64            // K_DIM/64
#define NT_N2 43            // N_DIM/256
#define ATB   32768         // one 256x64 fp16 tile = 32 KB
#define XH_BYTES  33554432ull                 // 16*64*32768 (A tiles)
#define WT_BYTES  90177536ull                 // 43*64*32768 (B tiles)

typedef _Float16 f16x8 __attribute__((ext_vector_type(8)));
typedef float    f32x4 __attribute__((ext_vector_type(4)));

#define SB()    __builtin_amdgcn_sched_barrier(0)
#define VMW(N)  do { asm volatile("s_waitcnt vmcnt(" #N ")" ::: "memory"); SB(); } while (0)

// 1 int32 -> 8 fp16 dequant, (k,k+4)-interleaved order
__device__ __forceinline__ f16x8 dq8(unsigned q, __half2 scp, __half2 nzp)
{
    const unsigned mu = 0xE400E400u;
    const __half2 m1024 = *(const __half2*)&mu;
    union { __half2 h2[4]; f16x8 v; } p;
#pragma unroll
    for (int d = 0; d < 4; ++d) {
        unsigned t = ((q >> (4 * d)) & 0x000F000Fu) | 0x64006400u;
        p.h2[d] = __hfma2(__hadd2(*(const __half2*)&t, m1024), scp, nzp);
    }
    return p.v;
}

// ---- A pre-pass: x f32 -> fp16, layout [mt16][kt64][kh2][sl4][row256][16B]
// chunk = 8 f16 of k = kt*64+kh*32+sl*8 in order (k0,k4,k1,k5,k2,k6,k3,k7)
__global__ __launch_bounds__(256)
void r22_xcvt(const float* __restrict__ x, __half* __restrict__ xh, int nchunks)
{
    int c = blockIdx.x * 256 + threadIdx.x;
    const int stride = gridDim.x * 256;
    for (; c < nchunks; c += stride) {
        const int row = c & 255;
        const int sl  = (c >> 8) & 3;
        const int kh  = (c >> 10) & 1;
        const int tl  = c >> 11;
        const int mt  = tl >> 6;
        const int kt  = tl & 63;
        const size_t gm = (size_t)mt * 256 + row;
        const int kb = kt * 64 + kh * 32 + sl * 8;
        const float4 f0 = *(const float4*)(x + gm * K_DIM + kb);
        const float4 f1 = *(const float4*)(x + gm * K_DIM + kb + 4);
        union { __half2 h2[4]; int4 v; } p;
        p.h2[0] = __floats2half2_rn(f0.x, f1.x);
        p.h2[1] = __floats2half2_rn(f0.y, f1.y);
        p.h2[2] = __floats2half2_rn(f0.z, f1.z);
        p.h2[3] = __floats2half2_rn(f0.w, f1.w);
        ((int4*)xh)[c] = p.v;
    }
}

// ---- W pre-pass: int4 -> fp16 once, layout [nt43][kt64][kh2][sl4][n256][16B]
// chunk (nt,kt,kh,sl,n) = dq8(qweight[kt*8+kh*4+sl][n]) with group kt>>1.
__global__ __launch_bounds__(256)
void r22_wcvt(const int* __restrict__ qweight, const int* __restrict__ qzeros,
              const float* __restrict__ scales, __half* __restrict__ wt, int nchunks)
{
    int c = blockIdx.x * 256 + threadIdx.x;
    const int stride = gridDim.x * 256;
    for (; c < nchunks; c += stride) {
        const int nl = c & 255;
        const int sl = (c >> 8) & 3;
        const int kh = (c >> 10) & 1;
        const int kt = (c >> 11) & 63;
        const int nt = c >> 17;
        const int n  = nt * 256 + nl;
        const int g  = kt >> 1;
        const unsigned q = (unsigned)qweight[(size_t)(kt * 8 + kh * 4 + sl) * N_DIM + n];
        const float s = scales[(size_t)g * N_DIM + n];
        const unsigned zq = (unsigned)qzeros[(size_t)g * NZ8 + (n >> 3)];
        const float zf = (float)((zq >> ((n & 7) * 4)) & 15u);
        const __half sh = __float2half_rn(s), nh = __float2half_rn(-s * zf);
        const f16x8 v = dq8(q, __half2(sh, sh), __half2(nh, nh));
        *(f16x8*)(wt + (size_t)c * 8) = v;
    }
}

// ---- dense GEMM: 256x256 tile, BK=64, 4 waves of 128x128, both operands
// staged via global_load_lds from pre-formatted ws. One barrier per k-tile;
// next-tile loads issued at tile top (drain at barrier is free-by-time).
__global__ __launch_bounds__(256, 1)
void r22_gemm(const __half* __restrict__ xh,
              const __half* __restrict__ wt,
              const float* __restrict__ bias,
              float* __restrict__ out)
{
    __shared__ __align__(16) unsigned char Ab[2][ATB];   // 64 KB
    __shared__ __align__(16) unsigned char Bb[2][ATB];   // 64 KB

    const int tid  = threadIdx.x;
    const int lane = tid & 63;
    const int wid  = tid >> 6;           // 0..3
    const int wr   = (wid >> 1) * 128;   // wave M offset (0,128)
    const int wc   = (wid & 1) * 128;    // wave N offset (0,128)

    int bid = blockIdx.x;                // XCD swizzle (688 = 8*86)
    const int cpx = gridDim.x >> 3;
    bid = (bid & 7) * cpx + (bid >> 3);
    const int mt = bid / NT_N2;          // 0..15
    const int nt = bid % NT_N2;          // 0..42

    const int frow = lane & 15, kb8 = lane >> 4;
    const int aOff = kb8 * 4096 + (wr + frow) * 16;
    const int bOff = kb8 * 4096 + (wc + frow) * 16;

    const char* agp = (const char*)xh + (size_t)mt * NKT * ATB + tid * 16;
    const char* bgp = (const char*)wt + (size_t)nt * NKT * ATB + tid * 16;

    f32x4 acc[8][8];
#pragma unroll
    for (int m = 0; m < 8; ++m)
#pragma unroll
        for (int n = 0; n < 8; ++n)
            acc[m][n] = (f32x4){0.f, 0.f, 0.f, 0.f};

    // prologue: stage tile 0
#pragma unroll
    for (int j = 0; j < 8; ++j) {
        __builtin_amdgcn_global_load_lds((const unsigned int*)(agp + j * 4096),
            (unsigned int*)&Ab[0][j * 4096 + tid * 16], 16, 0, 0);
        __builtin_amdgcn_global_load_lds((const unsigned int*)(bgp + j * 4096),
            (unsigned int*)&Bb[0][j * 4096 + tid * 16], 16, 0, 0);
    }
    __syncthreads();

    for (int t = 0; t < NKT; ++t) {
        const int cur = t & 1;
        if (t + 1 < NKT) {
            const char* an = agp + (size_t)(t + 1) * ATB;
            const char* bn = bgp + (size_t)(t + 1) * ATB;
#pragma unroll
            for (int j = 0; j < 8; ++j) {
                __builtin_amdgcn_global_load_lds((const unsigned int*)(an + j * 4096),
                    (unsigned int*)&Ab[cur ^ 1][j * 4096 + tid * 16], 16, 0, 0);
                __builtin_amdgcn_global_load_lds((const unsigned int*)(bn + j * 4096),
                    (unsigned int*)&Bb[cur ^ 1][j * 4096 + tid * 16], 16, 0, 0);
            }
        }
        const unsigned char* Ac = &Ab[cur][0];
        const unsigned char* Bc = &Bb[cur][0];
#pragma unroll
        for (int kh = 0; kh < 2; ++kh) {
            f16x8 af[8], bf[8];
#pragma unroll
            for (int m = 0; m < 8; ++m)
                af[m] = *(const f16x8*)(Ac + kh * 16384 + aOff + m * 256);
#pragma unroll
            for (int n = 0; n < 8; ++n)
                bf[n] = *(const f16x8*)(Bc + kh * 16384 + bOff + n * 256);
            __builtin_amdgcn_s_setprio(1);
#pragma unroll
            for (int m = 0; m < 8; ++m)
#pragma unroll
                for (int n = 0; n < 8; ++n)
                    acc[m][n] = __builtin_amdgcn_mfma_f32_16x16x32_f16(
                        af[m], bf[n], acc[m][n], 0, 0, 0);
            __builtin_amdgcn_s_setprio(0);
        }
        __syncthreads();
    }

    // epilogue: C row=(lane>>4)*4+j, col=lane&15 (m89 layout)
    const int crow0 = (lane >> 4) << 2, ccol = lane & 15;
#pragma unroll
    for (int n = 0; n < 8; ++n) {
        const int col = nt * 256 + wc + n * 16 + ccol;
        const float bv = bias[col];
#pragma unroll
        for (int m = 0; m < 8; ++m) {
            const int row = mt * 256 + wr + m * 16 + crow0;
#pragma unroll
            for (int j = 0; j < 4; ++j)
                out[(size_t)(row + j) * N_DIM + col] = acc[m][n][j] + bv;
        }
    }
}

// ================= fallback 1: r15 fused kernel (ws >= 33.6 MB) =============
#define ISSUE_Q8(D0,D1,D2,D3,D4,D5,D6,D7) do { \
    asm volatile( \
        "global_load_dword %0, %8, off\n\t" \
        "global_load_dword %1, %8, off offset:64\n\t" \
        "global_load_dword %2, %8, off offset:128\n\t" \
        "global_load_dword %3, %8, off offset:192\n\t" \
        "global_load_dword %4, %9, off\n\t" \
        "global_load_dword %5, %9, off offset:64\n\t" \
        "global_load_dword %6, %9, off offset:128\n\t" \
        "global_load_dword %7, %9, off offset:192" \
        : "=&v"(D0), "=&v"(D1), "=&v"(D2), "=&v"(D3), \
          "=&v"(D4), "=&v"(D5), "=&v"(D6), "=&v"(D7) \
        : "v"(qp0), "v"(qp1) : "memory"); \
    qp0 += 8 * N_DIM; qp1 += 8 * N_DIM; \
} while (0)

#define ISSUE_SZ() do { \
    asm volatile( \
        "global_load_dword %0, %8, off\n\t" \
        "global_load_dword %1, %8, off offset:64\n\t" \
        "global_load_dword %2, %8, off offset:128\n\t" \
        "global_load_dword %3, %8, off offset:192\n\t" \
        "global_load_dword %4, %9, off\n\t" \
        "global_load_dword %5, %9, off offset:8\n\t" \
        "global_load_dword %6, %9, off offset:16\n\t" \
        "global_load_dword %7, %9, off offset:24" \
        : "=&v"(sS0), "=&v"(sS1), "=&v"(sS2), "=&v"(sS3), \
          "=&v"(sZ0), "=&v"(sZ1), "=&v"(sZ2), "=&v"(sZ3) \
        : "v"(sp), "v"(zp) : "memory"); \
    sp += N_DIM; zp += NZ8; \
} while (0)

#define ISSUE_A(BUFP, T) do { \
    const char* _s = agp + (size_t)(T) * ATB; \
    _Pragma("unroll") for (int j = 0; j < 4; ++j) \
        __builtin_amdgcn_global_load_lds((const unsigned int*)(_s + j * 8192), \
            (unsigned int*)((BUFP) + j * 8192 + tid * 16), 16, 0, 0); \
} while (0)

#define FRAGS(ARp, KH) do { \
    _Pragma("unroll") for (int m = 0; m < 8; ++m) \
        af[m] = *(const f16x8*)((ARp) + (KH) * 16384 + aOff + m * 256); \
} while (0)

#define DQ4(Q0,Q1,Q2,Q3) do { \
    bf[0] = dq8(Q0, scp0, nzp0); bf[1] = dq8(Q1, scp1, nzp1); \
    bf[2] = dq8(Q2, scp2, nzp2); bf[3] = dq8(Q3, scp3, nzp3); \
} while (0)

#define MFMA32() do { \
    __builtin_amdgcn_s_setprio(1); \
    _Pragma("unroll") for (int m = 0; m < 8; ++m) \
        _Pragma("unroll") for (int n = 0; n < 4; ++n) \
            acc[m][n] = __builtin_amdgcn_mfma_f32_16x16x32_f16(af[m], bf[n], acc[m][n], 0, 0, 0); \
    __builtin_amdgcn_s_setprio(0); \
    SB(); \
} while (0)

#define CVT_S() do { \
    const float _s0 = __uint_as_float(sS0), _s1 = __uint_as_float(sS1); \
    const float _s2 = __uint_as_float(sS2), _s3 = __uint_as_float(sS3); \
    const __half _h0 = __float2half_rn(_s0), _h1 = __float2half_rn(_s1); \
    const __half _h2 = __float2half_rn(_s2), _h3 = __float2half_rn(_s3); \
    scp0 = __half2(_h0, _h0); scp1 = __half2(_h1, _h1); \
    scp2 = __half2(_h2, _h2); scp3 = __half2(_h3, _h3); \
    const __half _n0 = __float2half_rn(-_s0 * (float)((sZ0 >> sh4) & 15u)); \
    const __half _n1 = __float2half_rn(-_s1 * (float)((sZ1 >> sh4) & 15u)); \
    const __half _n2 = __float2half_rn(-_s2 * (float)((sZ2 >> sh4) & 15u)); \
    const __half _n3 = __float2half_rn(-_s3 * (float)((sZ3 >> sh4) & 15u)); \
    nzp0 = __half2(_n0, _n0); nzp1 = __half2(_n1, _n1); \
    nzp2 = __half2(_n2, _n2); nzp3 = __half2(_n3, _n3); \
} while (0)

__global__ __launch_bounds__(512, 2)
void r22_fused(const __half* __restrict__ xh,
               const int*   __restrict__ qweight,
               const int*   __restrict__ qzeros,
               const float* __restrict__ scales,
               const float* __restrict__ bias,
               float* __restrict__ out)
{
    __shared__ __align__(16) unsigned char A0s[ATB], A1s[ATB];

    const int tid  = threadIdx.x;
    const int lane = tid & 63;
    const int wid  = tid >> 6;
    const int wr   = (wid >> 2) * 128;
    const int wc   = (wid & 3) * 64;

    int bid = blockIdx.x;
    const int cpx = gridDim.x >> 3;
    bid = (bid & 7) * cpx + (bid >> 3);
    const int bm0 = (bid / NT_N2) * 256;
    const int bn0 = (bid % NT_N2) * 256;

    const int frow = lane & 15, kb8 = lane >> 4;
    const int ngl2 = bn0 + wc + frow;
    const int sh4  = (ngl2 & 7) * 4;
    const int aOff = kb8 * 4096 + (wr + frow) * 16;

    const char* agp = (const char*)xh + ((size_t)(bm0 >> 8) * NKT) * ATB + tid * 16;

    const int*   qp0 = qweight + (size_t)kb8 * N_DIM + ngl2;
    const int*   qp1 = qweight + (size_t)(kb8 + 4) * N_DIM + ngl2;
    const float* sp  = scales + (size_t)N_DIM + ngl2;
    const int*   zp  = qzeros + (size_t)NZ8 + (ngl2 >> 3);

    unsigned char *aR = A0s, *aW = A1s;

    f32x4 acc[8][4];
#pragma unroll
    for (int m = 0; m < 8; ++m)
#pragma unroll
        for (int n = 0; n < 4; ++n)
            acc[m][n] = (f32x4){0.f, 0.f, 0.f, 0.f};
    f16x8 af[8], bf[4];
    __half2 scp0, scp1, scp2, scp3, nzp0, nzp1, nzp2, nzp3;
    unsigned qa0, qa1, qa2, qa3, qa4, qa5, qa6, qa7;
    unsigned qb0, qb1, qb2, qb3, qb4, qb5, qb6, qb7;
    unsigned sS0, sS1, sS2, sS3, sZ0, sZ1, sZ2, sZ3;

    sS0 = __float_as_uint(scales[ngl2]);
    sS1 = __float_as_uint(scales[ngl2 + 16]);
    sS2 = __float_as_uint(scales[ngl2 + 32]);
    sS3 = __float_as_uint(scales[ngl2 + 48]);
    sZ0 = (unsigned)qzeros[(ngl2 >> 3) + 0];
    sZ1 = (unsigned)qzeros[(ngl2 >> 3) + 2];
    sZ2 = (unsigned)qzeros[(ngl2 >> 3) + 4];
    sZ3 = (unsigned)qzeros[(ngl2 >> 3) + 6];
    asm volatile("" : "+v"(sS0), "+v"(sS1), "+v"(sS2), "+v"(sS3),
                      "+v"(sZ0), "+v"(sZ1), "+v"(sZ2), "+v"(sZ3));
    VMW(0);
    ISSUE_Q8(qa0, qa1, qa2, qa3, qa4, qa5, qa6, qa7);
    ISSUE_A(aR, 0);
    ISSUE_Q8(qb0, qb1, qb2, qb3, qb4, qb5, qb6, qb7);
    ISSUE_A(aW, 1);
    VMW(12);
    __builtin_amdgcn_s_barrier();

    for (int u = 0; u < 31; ++u) {
        const int t0 = 2 * u;
        CVT_S();
        FRAGS(aR, 0); DQ4(qa0, qa1, qa2, qa3);
        asm volatile("s_waitcnt lgkmcnt(0)" ::: "memory"); SB();
        MFMA32();
        FRAGS(aR, 1); DQ4(qa4, qa5, qa6, qa7);
        ISSUE_Q8(qa0, qa1, qa2, qa3, qa4, qa5, qa6, qa7);
        ISSUE_SZ();
        asm volatile("s_waitcnt lgkmcnt(0)" ::: "memory"); SB();
        MFMA32();
        VMW(16);
        __builtin_amdgcn_s_barrier(); SB();
        { unsigned char* tp = aR; aR = aW; aW = tp; }
        ISSUE_A(aW, t0 + 2);
        FRAGS(aR, 0); DQ4(qb0, qb1, qb2, qb3);
        asm volatile("s_waitcnt lgkmcnt(0)" ::: "memory"); SB();
        MFMA32();
        FRAGS(aR, 1); DQ4(qb4, qb5, qb6, qb7);
        ISSUE_Q8(qb0, qb1, qb2, qb3, qb4, qb5, qb6, qb7);
        asm volatile("s_waitcnt lgkmcnt(0)" ::: "memory"); SB();
        MFMA32();
        VMW(8);
        __builtin_amdgcn_s_barrier(); SB();
        { unsigned char* tp = aR; aR = aW; aW = tp; }
        ISSUE_A(aW, t0 + 3);
    }

    CVT_S();
    FRAGS(aR, 0); DQ4(qa0, qa1, qa2, qa3);
    asm volatile("s_waitcnt lgkmcnt(0)" ::: "memory"); SB();
    MFMA32();
    FRAGS(aR, 1); DQ4(qa4, qa5, qa6, qa7);
    asm volatile("s_waitcnt lgkmcnt(0)" ::: "memory"); SB();
    MFMA32();
    VMW(0);
    __builtin_amdgcn_s_barrier(); SB();
    { unsigned char* tp = aR; aR = aW; aW = tp; }
    FRAGS(aR, 0); DQ4(qb0, qb1, qb2, qb3);
    asm volatile("s_waitcnt lgkmcnt(0)" ::: "memory"); SB();
    MFMA32();
    FRAGS(aR, 1); DQ4(qb4, qb5, qb6, qb7);
    asm volatile("s_waitcnt lgkmcnt(0)" ::: "memory"); SB();
    MFMA32();

    const int crow0 = (lane >> 4) << 2, ccol = lane & 15;
#pragma unroll
    for (int n = 0; n < 4; ++n) {
        const int col = bn0 + wc + n * 16 + ccol;
        const float bv = bias[col];
#pragma unroll
        for (int m = 0; m < 8; ++m) {
            const int row = bm0 + wr + m * 16 + crow0;
#pragma unroll
            for (int j = 0; j < 4; ++j)
                out[(size_t)(row + j) * N_DIM + col] = acc[m][n][j] + bv;
        }
    }
}

extern "C" void kernel_launch(void* const* d_in, const int* in_sizes, int n_in,
                              void* d_out, int out_size, void* d_ws, size_t ws_size,
                              hipStream_t stream)
{
    const float* x   = (const float*)d_in[0];
    const int*   qw  = (const int*)d_in[1];
    const int*   qz  = (const int*)d_in[2];
    const float* scl = (const float*)d_in[3];
    const float* bs  = (const float*)d_in[4];
    float* out = (float*)d_out;

    const int M = in_sizes[0] / K_DIM;               // 4096
    const int na = M * K_DIM / 8;                    // A chunks

    if (ws_size >= XH_BYTES + WT_BYTES) {
        // dense path: pre-dequant W + pre-convert A, then pure fp16 GEMM
        __half* xh = (__half*)d_ws;
        __half* wt = (__half*)((char*)d_ws + XH_BYTES);
        hipLaunchKernelGGL(r22_xcvt, dim3(2048), dim3(256), 0, stream, x, xh, na);
        hipLaunchKernelGGL(r22_wcvt, dim3(2048), dim3(256), 0, stream,
                           qw, qz, scl, wt, (int)(WT_BYTES / 16));
        dim3 grid((M / 256) * NT_N2);                // 688
        hipLaunchKernelGGL(r22_gemm, grid, dim3(256), 0, stream,
                           xh, wt, bs, out);
    } else {
        // fallback: proven r15 fused kernel
        __half* xh = (__half*)d_ws;
        hipLaunchKernelGGL(r22_xcvt, dim3(2048), dim3(256), 0, stream, x, xh, na);
        dim3 grid((M / 256) * NT_N2);                // 688
        hipLaunchKernelGGL(r22_fused, grid, dim3(512), 0, stream,
                           xh, qw, qz, scl, bs, out);
    }
}